// Round 11
// baseline (205.681 us; speedup 1.0000x reference)
//
#include <hip/hip_runtime.h>
#include <cmath>

#define EPSF 1e-15f
#define MAXN 0.99999f            // (1 - 1e-5) / sqrt(c), c=1

// ---- workspace layout (float offsets) -------------------------------------
#define OFF_ZU1  0               // 450  normalized z1 columns [75][6]
#define OFF_P1   512             // 18   zn1[6], ch1[6], sh1[6]
#define OFF_ZU2  576             // 2400 normalized z2 columns [150][16]
#define OFF_P2   3072            // 48   zn2[16], ch2[16], sh2[16]
#define OFF_PF1  3200            // 360  znf1[120]*3
#define OFF_PF2  3584            // 252  znf2[84]*3
#define OFF_PF3  3904            // 30   znf3[10]*3

// ---- single-instruction math (v_rcp_f32 / v_sqrt_f32, ~1 ulp) -------------
__device__ __forceinline__ float frcp(float x)  { return __builtin_amdgcn_rcpf(x); }
__device__ __forceinline__ float fsqrt(float x) { return __builtin_amdgcn_sqrtf(x); }

// ---- fast transcendentals -------------------------------------------------
__device__ __forceinline__ float fast_tanh_pos(float x) {   // x >= 0
    float e = __expf(-2.0f * x);
    return (1.0f - e) * frcp(1.0f + e);
}
__device__ __forceinline__ float fast_atanh01(float x) {    // 0 <= x < 1
    return 0.5f * __logf((1.0f + x) * frcp(1.0f - x));
}
// sinh(k * asinh(t)) = sign(t) * 0.5 * (q^k - q^-k), q = |t| + sqrt(t^2+1)
__device__ __forceinline__ float sinh_k_asinh(float t, float k) {
    float at = fabsf(t);
    float lq = __logf(at + fsqrt(fmaf(at, at, 1.0f)));
    float p = __expf(k * lq);
    float r = 0.5f * (p - frcp(p));
    return t < 0.f ? -r : r;
}

__device__ __forceinline__ float wave_reduce_sum(float s) {
#pragma unroll
    for (int d = 1; d < 64; d <<= 1) s += __shfl_xor(s, d);
    return s;
}

// block-wide sum over 256 threads; all threads must call.
__device__ __forceinline__ float block_reduce(float v, float* rbuf, int tid) {
    float s = wave_reduce_sum(v);
    __syncthreads();                       // protect rbuf from previous use
    if ((tid & 63) == 0) rbuf[tid >> 6] = s;
    __syncthreads();
    return rbuf[0] + rbuf[1] + rbuf[2] + rbuf[3];
}

// ---------------------------------------------------------------------------
// P0: weight prep, one block per matrix (5 blocks x 256 thr). Coalesced
// element reads + LDS atomic per-column accumulation (const DOUT -> magic
// mul for %), then finalize zn/cosh/sinh and (conv) normalized columns.
// ---------------------------------------------------------------------------
template<int DIN, int DOUT>
__device__ __forceinline__ void prep_one(const float* __restrict__ z,
        const float* __restrict__ r, float* __restrict__ zu,
        float* __restrict__ par, float* acc) {
    int tid = threadIdx.x;
    for (int i = tid; i < DOUT; i += 256) acc[i] = 0.f;
    __syncthreads();
    for (int i = tid; i < DIN * DOUT; i += 256) {
        float w = z[i];
        atomicAdd(&acc[i % DOUT], w * w);
    }
    __syncthreads();
    for (int o = tid; o < DOUT; o += 256) {
        float zn = fmaxf(fsqrt(acc[o]), EPSF);
        par[o] = zn;
        par[DOUT + o]     = coshf(2.0f * r[o]);
        par[2 * DOUT + o] = sinhf(2.0f * r[o]);
    }
    __syncthreads();
    if (zu) {
        for (int o = tid; o < DOUT; o += 256) acc[o] = frcp(par[o]);
        __syncthreads();
        for (int i = tid; i < DIN * DOUT; i += 256) zu[i] = z[i] * acc[i % DOUT];
    }
}

__global__ __launch_bounds__(256) void prep_kernel(
        const float* __restrict__ z1, const float* __restrict__ r1,
        const float* __restrict__ z2, const float* __restrict__ r2,
        const float* __restrict__ zf1, const float* __restrict__ rf1,
        const float* __restrict__ zf2, const float* __restrict__ rf2,
        const float* __restrict__ zf3, const float* __restrict__ rf3,
        float* __restrict__ ws) {
    __shared__ float acc[128];
    switch (blockIdx.x) {
    case 0: prep_one<75, 6>   (z1,  r1,  ws + OFF_ZU1, ws + OFF_P1,  acc); break;
    case 1: prep_one<150, 16> (z2,  r2,  ws + OFF_ZU2, ws + OFF_P2,  acc); break;
    case 2: prep_one<400, 120>(zf1, rf1, nullptr,      ws + OFF_PF1, acc); break;
    case 3: prep_one<120, 84> (zf2, rf2, nullptr,      ws + OFF_PF2, acc); break;
    default:prep_one<84, 10>  (zf3, rf3, nullptr,      ws + OFF_PF3, acc); break;
    }
}

// ---------------------------------------------------------------------------
// chain (all channels in-thread): expmap0 -> poincare_fc -> project -> hrelu.
// ---------------------------------------------------------------------------
template<int N>
__device__ __forceinline__ float chain_fast(float (&a)[N], float n2,
        const float (&zn)[N], const float (&ch)[N], const float (&sh)[N]) {
    float nn = fmaxf(fsqrt(n2), EPSF);
    float t = fast_tanh_pos(nn);
    float s = t * frcp(nn) * fminf(1.0f, MAXN * frcp(fmaxf(t, EPSF)));
    float cx2 = (s * s) * n2;
    float rden = frcp(fmaxf(1.0f - cx2, EPSF));
    float ys2 = 0.f;
#pragma unroll
    for (int o = 0; o < N; o++) {
        float arg = (2.0f * (s * a[o]) * ch[o] - (1.0f + cx2) * sh[o]) * rden;
        float yy = sinh_k_asinh(arg, 2.0f * zn[o]);
        a[o] = yy; ys2 += yy * yy;
    }
    float dnm = 1.0f + fsqrt(1.0f + ys2);
    float ny2 = ys2 * frcp(dnm * dnm);
    float ny = fmaxf(fsqrt(ny2), EPSF);
    float pf = fminf(1.0f, MAXN * frcp(ny));
    float sc = pf * frcp(dnm);
    float n2b = pf * pf * ny2;
    float nb = fmaxf(fsqrt(n2b), EPSF);
    float fb = fast_atanh01(fminf(nb, 1.0f - 1e-7f)) * frcp(nb);
    float m2 = 0.f;
#pragma unroll
    for (int o = 0; o < N; o++) { float uu = fmaxf(fb * sc * a[o], 0.f); a[o] = uu; m2 += uu * uu; }
    float m = fmaxf(fsqrt(m2), EPSF);
    float tm = fast_tanh_pos(m);
    float g = tm * frcp(m) * fminf(1.0f, MAXN * frcp(fmaxf(tm, EPSF)));
#pragma unroll
    for (int o = 0; o < N; o++) a[o] *= g;
    return g * g * m2;
}

// ---------------------------------------------------------------------------
// FC layer, block-level. 2 threads per output column (half-dots, combined by
// lane-pair shuffle). dst gets pre-g values for RELU layers (g folded into
// the NEXT layer via gnext); final layer writes sc*y directly.
// ---------------------------------------------------------------------------
template<int DIN, int DOUT, bool RELU>
__device__ __forceinline__ float fc_block(int tid, const float* __restrict__ xin,
        float gin, float cx2, const float* __restrict__ zg,
        const float* __restrict__ parw, float* __restrict__ dst,
        float* rbuf, float& gnext) {
    constexpr int H = DIN / 2;            // DIN even for all layers
    int col = tid >> 1, half = tid & 1;
    bool act = tid < 2 * DOUT;
    float d = 0.f;
    if (act) {
        float a0 = 0.f, a1 = 0.f;
        int f0 = half * H;
        for (int f = f0; f < f0 + H; f += 2) {
            a0 = fmaf(xin[f],     zg[f * DOUT + col],       a0);
            a1 = fmaf(xin[f + 1], zg[(f + 1) * DOUT + col], a1);
        }
        d = a0 + a1;
    }
    d += __shfl_xor(d, 1);                // combine halves (pairs aligned)
    d *= gin;
    float y = 0.f;
    float rden = frcp(fmaxf(1.0f - cx2, EPSF));
    if (act) {
        float zn = parw[col], chv = parw[DOUT + col], shv = parw[2 * DOUT + col];
        float arg = (2.0f * (d * frcp(zn)) * chv - (1.0f + cx2) * shv) * rden;
        y = sinh_k_asinh(arg, 2.0f * zn);
    }
    float ys2 = block_reduce((act && half == 0) ? y * y : 0.f, rbuf, tid);
    float dnm = 1.0f + fsqrt(1.0f + ys2);
    float ny2 = ys2 * frcp(dnm * dnm);
    float ny = fmaxf(fsqrt(ny2), EPSF);
    float pf = fminf(1.0f, MAXN * frcp(ny));
    float sc = pf * frcp(dnm);
    if (!RELU) {
        if (act && half == 0) dst[col] = sc * y;
        gnext = 1.f;
        return 0.f;
    }
    float n2b = pf * pf * ny2;
    float nb = fmaxf(fsqrt(n2b), EPSF);
    float fb = fast_atanh01(fminf(nb, 1.0f - 1e-7f)) * frcp(nb);
    float u = fmaxf(fb * sc * y, 0.f);
    if (act && half == 0) dst[col] = u;   // pre-g; next barrier publishes
    float m2 = block_reduce((act && half == 0) ? u * u : 0.f, rbuf, tid);
    float m = fmaxf(fsqrt(m2), EPSF);
    float tm = fast_tanh_pos(m);
    float g = tm * frcp(m) * fminf(1.0f, MAXN * frcp(fmaxf(tm, EPSF)));
    gnext = g;
    return g * g * m2;
}

// ---------------------------------------------------------------------------
// MEGA: whole net, one block per image.
// ---------------------------------------------------------------------------
__global__ __launch_bounds__(256) void mega_kernel(const float* __restrict__ x,
        const float* __restrict__ ws, const float* __restrict__ zf1,
        const float* __restrict__ zf2, const float* __restrict__ zf3,
        float* __restrict__ out, float ratio1, float ratio2, float ratio3) {
    __shared__ float xv[3168];            // [3][32][33]
    __shared__ float z2s[2400];           // z2 unit columns [150][16]
    __shared__ float par2[48];
    __shared__ float v2[1260];            // conv1 out, logmap'd [6][14][15]
    __shared__ float rs[140];             // conv2 patch-norm row sums [14][10]
    __shared__ float u3[400];             // flatten (pre-g)
    __shared__ float h1[120];
    __shared__ float h2[84];
    __shared__ float spart[5];
    __shared__ float rbuf[4];
    int b = blockIdx.x, tid = threadIdx.x;

    // ---- A: stage input + conv2 weights ----
    for (int i = tid; i < 3072; i += 256) {
        int c = i >> 10, rem = i & 1023;
        xv[c * 1056 + (rem >> 5) * 33 + (rem & 31)] = x[(size_t)b * 3072 + i];
    }
    for (int i = tid; i < 2400; i += 256) z2s[i] = ws[OFF_ZU2 + i];
    if (tid < 48) par2[tid] = ws[OFF_P2 + tid];
    __syncthreads();

    // ---- B: logmap0 over channels of x ----
    for (int p = tid; p < 1024; p += 256) {
        int base = (p >> 5) * 33 + (p & 31);
        float a0 = xv[base], a1 = xv[1056 + base], a2 = xv[2112 + base];
        float n2 = a0 * a0 + a1 * a1 + a2 * a2;
        float nn = fmaxf(fsqrt(n2), EPSF);
        float f = fast_atanh01(fminf(nn, 1.0f - 1e-7f)) * frcp(nn) * ratio1;
        xv[base] = a0 * f; xv[1056 + base] = a1 * f; xv[2112 + base] = a2 * f;
    }
    __syncthreads();

    // ---- C: conv1 + hrelu + pool (thread = pooled cell), fused logmap2 ----
    if (tid < 196) {
        const float* zug  = ws + OFF_ZU1;
        const float* parg = ws + OFF_P1;
        int ph = tid / 14, pw = tid % 14;
        int base0 = (2 * ph) * 33 + 2 * pw;
        float acc[4][6], n2w[4];
#pragma unroll
        for (int wi = 0; wi < 4; wi++) {
            n2w[wi] = 0.f;
#pragma unroll
            for (int o = 0; o < 6; o++) acc[wi][o] = 0.f;
        }
#pragma unroll 1
        for (int c = 0; c < 3; c++) {
            float px[6][6];
#pragma unroll
            for (int r = 0; r < 6; r++)
#pragma unroll
            for (int j = 0; j < 6; j++)
                px[r][j] = xv[c * 1056 + base0 + r * 33 + j];
#pragma unroll
            for (int fi = 0; fi < 5; fi++) {
                const float* zp = zug + (c * 5 + fi) * 30;   // wave-uniform
#pragma unroll
                for (int fj = 0; fj < 5; fj++) {
                    float zw[6];
#pragma unroll
                    for (int o = 0; o < 6; o++) zw[o] = zp[fj * 6 + o];
#pragma unroll
                    for (int dy = 0; dy < 2; dy++)
#pragma unroll
                    for (int dx = 0; dx < 2; dx++) {
                        float v = px[fi + dy][fj + dx];
                        int wi = dy * 2 + dx;
                        n2w[wi] = fmaf(v, v, n2w[wi]);
#pragma unroll
                        for (int o = 0; o < 6; o++) acc[wi][o] = fmaf(v, zw[o], acc[wi][o]);
                    }
                }
            }
        }
        float zn[6], chv[6], shv[6];
#pragma unroll
        for (int o = 0; o < 6; o++) { zn[o] = parg[o]; chv[o] = parg[6 + o]; shv[o] = parg[12 + o]; }
        float best[6]; float bestn = -1.f;
#pragma unroll
        for (int wi = 0; wi < 4; wi++) {
            float hn2 = chain_fast<6>(acc[wi], n2w[wi], zn, chv, shv);
            if (hn2 > bestn) {
                bestn = hn2;
#pragma unroll
                for (int o = 0; o < 6; o++) best[o] = acc[wi][o];
            }
        }
        float nn = fmaxf(fsqrt(bestn), EPSF);
        float f2 = fast_atanh01(fminf(nn, 1.0f - 1e-7f)) * frcp(nn) * ratio2;
#pragma unroll
        for (int o = 0; o < 6; o++) v2[o * 210 + ph * 15 + pw] = f2 * best[o];
    }
    __syncthreads();

    // ---- D: conv2 patch-norm row sums rs[r][x] = sum_c sum_j v2[c][r][x+j]^2
    if (tid < 140) {
        int r = tid / 10, xq = tid % 10;
        float ssum = 0.f;
#pragma unroll
        for (int c = 0; c < 6; c++)
#pragma unroll
        for (int j = 0; j < 5; j++) {
            float v = v2[c * 210 + r * 15 + xq + j];
            ssum = fmaf(v, v, ssum);
        }
        rs[tid] = ssum;
    }
    __syncthreads();

    // ---- E: conv2 + hrelu + pool + flatten. thread = (window-row wy, chan o)
    if (tid < 160) {
        int wy = tid >> 4, o = tid & 15;
        float acc[10];
#pragma unroll
        for (int w = 0; w < 10; w++) acc[w] = 0.f;
#pragma unroll 1
        for (int c = 0; c < 6; c++) {
#pragma unroll 1
            for (int fi = 0; fi < 5; fi++) {
                float px[14];
#pragma unroll
                for (int k = 0; k < 14; k++) px[k] = v2[c * 210 + (wy + fi) * 15 + k];
#pragma unroll
                for (int fj = 0; fj < 5; fj++) {
                    float zw = z2s[((c * 5 + fi) * 5 + fj) * 16 + o];
#pragma unroll
                    for (int w = 0; w < 10; w++)
                        acc[w] = fmaf(px[w + fj], zw, acc[w]);
                }
            }
        }
        float znl = par2[o], chv = par2[16 + o], shv = par2[32 + o];
        float val[10], hn2v[10];
#pragma unroll
        for (int w = 0; w < 10; w++) {
            float n2 = rs[wy * 10 + w] + rs[(wy + 1) * 10 + w] + rs[(wy + 2) * 10 + w]
                     + rs[(wy + 3) * 10 + w] + rs[(wy + 4) * 10 + w];
            float nn = fmaxf(fsqrt(n2), EPSF);
            float t = fast_tanh_pos(nn);
            float s = t * frcp(nn) * fminf(1.0f, MAXN * frcp(fmaxf(t, EPSF)));
            float cx2 = (s * s) * n2;
            float rden = frcp(fmaxf(1.0f - cx2, EPSF));
            float arg = (2.0f * (s * acc[w]) * chv - (1.0f + cx2) * shv) * rden;
            float y = sinh_k_asinh(arg, 2.0f * znl);
            float p = y * y;
#pragma unroll
            for (int d = 1; d < 16; d <<= 1) p += __shfl_xor(p, d);
            float ys2 = p;
            float dnm = 1.0f + fsqrt(1.0f + ys2);
            float ny2 = ys2 * frcp(dnm * dnm);
            float ny = fmaxf(fsqrt(ny2), EPSF);
            float pf = fminf(1.0f, MAXN * frcp(ny));
            float sc = pf * frcp(dnm);
            float n2b = pf * pf * ny2;
            float nb = fmaxf(fsqrt(n2b), EPSF);
            float fb = fast_atanh01(fminf(nb, 1.0f - 1e-7f)) * frcp(nb);
            float u = fmaxf(fb * sc * y, 0.f);
            float q = u * u;
#pragma unroll
            for (int d = 1; d < 16; d <<= 1) q += __shfl_xor(q, d);
            float m2 = q;
            float m = fmaxf(fsqrt(m2), EPSF);
            float tm = fast_tanh_pos(m);
            float g = tm * frcp(m) * fminf(1.0f, MAXN * frcp(fmaxf(tm, EPSF)));
            val[w] = g * u;
            hn2v[w] = g * g * m2;
        }
        // pool 2x2 (first-max semantics) + flatten logmap factor
        float part = 0.f;
#pragma unroll
        for (int pw = 0; pw < 5; pw++) {
            int i0 = 2 * pw, i1 = i0 + 1;
            bool firstcol = hn2v[i0] >= hn2v[i1];
            float iu = firstcol ? val[i0]  : val[i1];
            float ih = firstcol ? hn2v[i0] : hn2v[i1];
            float pu  = __shfl_xor(iu, 16);   // partner row (wy ^ 1)
            float phh = __shfl_xor(ih, 16);
            if ((wy & 1) == 0) {
                bool top = ih >= phh;
                float wu = top ? iu : pu;
                float wh = top ? ih : phh;
                float nn = fmaxf(fsqrt(wh), EPSF);
                float f3 = fast_atanh01(fminf(nn, 1.0f - 1e-7f)) * frcp(nn) * ratio3;
                u3[o * 25 + (wy >> 1) * 5 + pw] = f3 * wu;
                if (o == 0) part = fmaf(f3 * f3, wh, part);
            }
        }
        if ((wy & 1) == 0 && o == 0) spart[wy >> 1] = part;
    }
    __syncthreads();

    // ---- F: flatten expmap scale + FC stack ----
    float S = spart[0] + spart[1] + spart[2] + spart[3] + spart[4];
    float nnS = fmaxf(fsqrt(S), EPSF);
    float tS = fast_tanh_pos(nnS);
    float gflat = tS * frcp(nnS) * fminf(1.0f, MAXN * frcp(fmaxf(tS, EPSF)));
    float cx2a = gflat * gflat * S;

    float g1, g2, gd;
    float cx2b = fc_block<400, 120, true >(tid, u3, gflat, cx2a, zf1, ws + OFF_PF1, h1, rbuf, g1);
    float cx2c = fc_block<120, 84,  true >(tid, h1, g1,   cx2b, zf2, ws + OFF_PF2, h2, rbuf, g2);
    fc_block<84, 10, false>(tid, h2, g2, cx2c, zf3, ws + OFF_PF3, out + (size_t)b * 10, rbuf, gd);
}

// ---------------------------------------------------------------------------
static double beta_fn(double n) {
    return exp(lgamma(n / 2.0) + lgamma(0.5) - lgamma((n + 1) / 2.0));
}

extern "C" void kernel_launch(void* const* d_in, const int* in_sizes, int n_in,
                              void* d_out, int out_size, void* d_ws, size_t ws_size,
                              hipStream_t stream) {
    (void)in_sizes; (void)n_in; (void)out_size; (void)ws_size;
    const float* x   = (const float*)d_in[0];
    const float* z1  = (const float*)d_in[1];
    const float* b1  = (const float*)d_in[2];
    const float* z2  = (const float*)d_in[3];
    const float* b2  = (const float*)d_in[4];
    const float* zf1 = (const float*)d_in[5];
    const float* bf1 = (const float*)d_in[6];
    const float* zf2 = (const float*)d_in[7];
    const float* bf2 = (const float*)d_in[8];
    const float* zf3 = (const float*)d_in[9];
    const float* bf3 = (const float*)d_in[10];
    float* out = (float*)d_out;
    float* ws  = (float*)d_ws;

    const float ratio1 = (float)(beta_fn(75.0)  / beta_fn(3.0));
    const float ratio2 = (float)(beta_fn(150.0) / beta_fn(6.0));
    const float ratio3 = (float)(beta_fn(400.0) / beta_fn(16.0));

    prep_kernel<<<5, 256, 0, stream>>>(z1, b1, z2, b2, zf1, bf1, zf2, bf2, zf3, bf3, ws);
    mega_kernel<<<1024, 256, 0, stream>>>(x, ws, zf1, zf2, zf3, out,
                                          ratio1, ratio2, ratio3);
}

// Round 13
// 162.085 us; speedup vs baseline: 1.2690x; 1.2690x over previous
//
#include <hip/hip_runtime.h>
#include <cmath>

#define EPSF 1e-15f
#define MAXN 0.99999f            // (1 - 1e-5) / sqrt(c), c=1

// ---- workspace layout (float offsets) -------------------------------------
#define OFF_ZU1  0               // 450  normalized z1 columns [75][6]
#define OFF_P1   512             // 18   zn1[6], ch1[6], sh1[6]
#define OFF_ZU2  576             // 2400 normalized z2 columns [150][16]
#define OFF_P2   3072            // 48   zn2[16], ch2[16], sh2[16]
#define OFF_PF1  3200            // 360  znf1[120]*3
#define OFF_PF2  3584            // 252  znf2[84]*3
#define OFF_PF3  3904            // 30   znf3[10]*3
#define OFF_ACC  4096            // 240  column sq-norm accumulators

// ---- single-instruction math (v_rcp_f32 / v_sqrt_f32, ~1 ulp) -------------
__device__ __forceinline__ float frcp(float x)  { return __builtin_amdgcn_rcpf(x); }
__device__ __forceinline__ float fsqrt(float x) { return __builtin_amdgcn_sqrtf(x); }

// ---- fast transcendentals -------------------------------------------------
__device__ __forceinline__ float fast_tanh_pos(float x) {   // x >= 0
    float e = __expf(-2.0f * x);
    return (1.0f - e) * frcp(1.0f + e);
}
__device__ __forceinline__ float fast_atanh01(float x) {    // 0 <= x < 1
    return 0.5f * __logf((1.0f + x) * frcp(1.0f - x));
}
// sinh(k * asinh(t)) = sign(t) * 0.5 * (q^k - q^-k), q = |t| + sqrt(t^2+1)
__device__ __forceinline__ float sinh_k_asinh(float t, float k) {
    float at = fabsf(t);
    float lq = __logf(at + fsqrt(fmaf(at, at, 1.0f)));
    float p = __expf(k * lq);
    float r = 0.5f * (p - frcp(p));
    return t < 0.f ? -r : r;
}

__device__ __forceinline__ float wave_reduce_sum(float s) {
#pragma unroll
    for (int d = 1; d < 64; d <<= 1) s += __shfl_xor(s, d);
    return s;
}

// block-wide sum over 256 threads; all threads must call.
__device__ __forceinline__ float block_reduce(float v, float* rbuf, int tid) {
    float s = wave_reduce_sum(v);
    __syncthreads();                       // protect rbuf from previous use
    if ((tid & 63) == 0) rbuf[tid >> 6] = s;
    __syncthreads();
    return rbuf[0] + rbuf[1] + rbuf[2] + rbuf[3];
}

// ---------------------------------------------------------------------------
// K0: zero accumulators + cosh/sinh (independent of column norms). 1 block.
// ---------------------------------------------------------------------------
__global__ __launch_bounds__(256) void init_kernel(
        const float* __restrict__ r1, const float* __restrict__ r2,
        const float* __restrict__ rf1, const float* __restrict__ rf2,
        const float* __restrict__ rf3, float* __restrict__ ws) {
    int t = threadIdx.x;
    if (t < 240) ws[OFF_ACC + t] = 0.f;
    const float* r; float* par; int Dout, o;
    if (t < 6)        { r = r1;  par = ws + OFF_P1;  Dout = 6;   o = t; }
    else if (t < 22)  { r = r2;  par = ws + OFF_P2;  Dout = 16;  o = t - 6; }
    else if (t < 142) { r = rf1; par = ws + OFF_PF1; Dout = 120; o = t - 22; }
    else if (t < 226) { r = rf2; par = ws + OFF_PF2; Dout = 84;  o = t - 142; }
    else if (t < 236) { r = rf3; par = ws + OFF_PF3; Dout = 10;  o = t - 226; }
    else return;
    float d = 2.0f * r[o];
    par[Dout + o]     = coshf(d);
    par[2 * Dout + o] = sinhf(d);
}

// ---------------------------------------------------------------------------
// K1: column sq-norm accumulate. One element per thread, coalesced reads,
// global atomicAdd per column (<=400 per address). 242 blocks x 256.
// ---------------------------------------------------------------------------
__global__ __launch_bounds__(256) void accum_kernel(
        const float* __restrict__ z1, const float* __restrict__ z2,
        const float* __restrict__ zf1, const float* __restrict__ zf2,
        const float* __restrict__ zf3, float* __restrict__ ws) {
    int gid = blockIdx.x * 256 + threadIdx.x;
    float w; int slot;
    if (gid < 450)        {                      w = z1[gid]; slot = 0   + gid % 6;  }
    else if (gid < 2850)  { int i = gid - 450;   w = z2[i];   slot = 6   + i % 16;  }
    else if (gid < 50850) { int i = gid - 2850;  w = zf1[i];  slot = 22  + i % 120; }
    else if (gid < 60930) { int i = gid - 50850; w = zf2[i];  slot = 142 + i % 84;  }
    else if (gid < 61770) { int i = gid - 60930; w = zf3[i];  slot = 226 + i % 10;  }
    else return;
    atomicAdd(&ws[OFF_ACC + slot], w * w);
}

// ---------------------------------------------------------------------------
// K2: finalize zn into par; write normalized conv columns. 4 blocks x 256.
// Each block derives zn it needs from acc directly (no inter-block dep).
// ---------------------------------------------------------------------------
__global__ __launch_bounds__(256) void final_kernel(
        const float* __restrict__ z1, const float* __restrict__ z2,
        float* __restrict__ ws) {
    int t = threadIdx.x, blk = blockIdx.x;
    const float* acc = ws + OFF_ACC;
    if (blk == 0) {
        if (t < 6)        ws[OFF_P1  + t]         = fmaxf(fsqrt(acc[t]), EPSF);
        else if (t < 22)  ws[OFF_P2  + (t - 6)]   = fmaxf(fsqrt(acc[t]), EPSF);
        else if (t < 142) ws[OFF_PF1 + (t - 22)]  = fmaxf(fsqrt(acc[t]), EPSF);
        else if (t < 226) ws[OFF_PF2 + (t - 142)] = fmaxf(fsqrt(acc[t]), EPSF);
        else if (t < 236) ws[OFF_PF3 + (t - 226)] = fmaxf(fsqrt(acc[t]), EPSF);
    } else if (blk == 1) {
        for (int i = t; i < 450; i += 256) {
            int col = i % 6;
            float rzn = frcp(fmaxf(fsqrt(acc[col]), EPSF));
            ws[OFF_ZU1 + i] = z1[i] * rzn;
        }
    } else {
        int base = (blk - 2) * 1200;
        for (int k = t; k < 1200; k += 256) {
            int i = base + k, col = i % 16;
            float rzn = frcp(fmaxf(fsqrt(acc[6 + col]), EPSF));
            ws[OFF_ZU2 + i] = z2[i] * rzn;
        }
    }
}

// ---------------------------------------------------------------------------
// chain (all channels in-thread): expmap0 -> poincare_fc -> project -> hrelu.
// ---------------------------------------------------------------------------
template<int N>
__device__ __forceinline__ float chain_fast(float (&a)[N], float n2,
        const float (&zn)[N], const float (&ch)[N], const float (&sh)[N]) {
    float nn = fmaxf(fsqrt(n2), EPSF);
    float t = fast_tanh_pos(nn);
    float s = t * frcp(nn) * fminf(1.0f, MAXN * frcp(fmaxf(t, EPSF)));
    float cx2 = (s * s) * n2;
    float rden = frcp(fmaxf(1.0f - cx2, EPSF));
    float ys2 = 0.f;
#pragma unroll
    for (int o = 0; o < N; o++) {
        float arg = (2.0f * (s * a[o]) * ch[o] - (1.0f + cx2) * sh[o]) * rden;
        float yy = sinh_k_asinh(arg, 2.0f * zn[o]);
        a[o] = yy; ys2 += yy * yy;
    }
    float dnm = 1.0f + fsqrt(1.0f + ys2);
    float ny2 = ys2 * frcp(dnm * dnm);
    float ny = fmaxf(fsqrt(ny2), EPSF);
    float pf = fminf(1.0f, MAXN * frcp(ny));
    float sc = pf * frcp(dnm);
    float n2b = pf * pf * ny2;
    float nb = fmaxf(fsqrt(n2b), EPSF);
    float fb = fast_atanh01(fminf(nb, 1.0f - 1e-7f)) * frcp(nb);
    float m2 = 0.f;
#pragma unroll
    for (int o = 0; o < N; o++) { float uu = fmaxf(fb * sc * a[o], 0.f); a[o] = uu; m2 += uu * uu; }
    float m = fmaxf(fsqrt(m2), EPSF);
    float tm = fast_tanh_pos(m);
    float g = tm * frcp(m) * fminf(1.0f, MAXN * frcp(fmaxf(tm, EPSF)));
#pragma unroll
    for (int o = 0; o < N; o++) a[o] *= g;
    return g * g * m2;
}

// ---------------------------------------------------------------------------
// FC layer, block-level. 2 threads per output column (half-dots, combined by
// lane-pair shuffle). dst gets pre-g values for RELU layers (g folded into
// the NEXT layer via gnext); final layer writes sc*y directly.
// ---------------------------------------------------------------------------
template<int DIN, int DOUT, bool RELU>
__device__ __forceinline__ float fc_block(int tid, const float* __restrict__ xin,
        float gin, float cx2, const float* __restrict__ zg,
        const float* __restrict__ parw, float* __restrict__ dst,
        float* rbuf, float& gnext) {
    constexpr int H = DIN / 2;            // DIN even for all layers
    int col = tid >> 1, half = tid & 1;
    bool act = tid < 2 * DOUT;
    float d = 0.f;
    if (act) {
        float a0 = 0.f, a1 = 0.f;
        int f0 = half * H;
        for (int f = f0; f < f0 + H; f += 2) {
            a0 = fmaf(xin[f],     zg[f * DOUT + col],       a0);
            a1 = fmaf(xin[f + 1], zg[(f + 1) * DOUT + col], a1);
        }
        d = a0 + a1;
    }
    d += __shfl_xor(d, 1);                // combine halves (pairs aligned)
    d *= gin;
    float y = 0.f;
    float rden = frcp(fmaxf(1.0f - cx2, EPSF));
    if (act) {
        float zn = parw[col], chv = parw[DOUT + col], shv = parw[2 * DOUT + col];
        float arg = (2.0f * (d * frcp(zn)) * chv - (1.0f + cx2) * shv) * rden;
        y = sinh_k_asinh(arg, 2.0f * zn);
    }
    float ys2 = block_reduce((act && half == 0) ? y * y : 0.f, rbuf, tid);
    float dnm = 1.0f + fsqrt(1.0f + ys2);
    float ny2 = ys2 * frcp(dnm * dnm);
    float ny = fmaxf(fsqrt(ny2), EPSF);
    float pf = fminf(1.0f, MAXN * frcp(ny));
    float sc = pf * frcp(dnm);
    if (!RELU) {
        if (act && half == 0) dst[col] = sc * y;
        gnext = 1.f;
        return 0.f;
    }
    float n2b = pf * pf * ny2;
    float nb = fmaxf(fsqrt(n2b), EPSF);
    float fb = fast_atanh01(fminf(nb, 1.0f - 1e-7f)) * frcp(nb);
    float u = fmaxf(fb * sc * y, 0.f);
    if (act && half == 0) dst[col] = u;   // pre-g; next barrier publishes
    float m2 = block_reduce((act && half == 0) ? u * u : 0.f, rbuf, tid);
    float m = fmaxf(fsqrt(m2), EPSF);
    float tm = fast_tanh_pos(m);
    float g = tm * frcp(m) * fminf(1.0f, MAXN * frcp(fmaxf(tm, EPSF)));
    gnext = g;
    return g * g * m2;
}

// ---------------------------------------------------------------------------
// MEGA: whole net, one block per image.
// ---------------------------------------------------------------------------
__global__ __launch_bounds__(256) void mega_kernel(const float* __restrict__ x,
        const float* __restrict__ ws, const float* __restrict__ zf1,
        const float* __restrict__ zf2, const float* __restrict__ zf3,
        float* __restrict__ out, float ratio1, float ratio2, float ratio3) {
    __shared__ float xv[3168];            // [3][32][33]
    __shared__ float z2s[2400];           // z2 unit columns [150][16]
    __shared__ float par2[48];
    __shared__ float v2[1260];            // conv1 out, logmap'd [6][14][15]
    __shared__ float rs[140];             // conv2 patch-norm row sums [14][10]
    __shared__ float u3[400];             // flatten (pre-g)
    __shared__ float h1[120];
    __shared__ float h2[84];
    __shared__ float spart[5];
    __shared__ float rbuf[4];
    int b = blockIdx.x, tid = threadIdx.x;

    // ---- A: stage input + conv2 weights ----
    for (int i = tid; i < 3072; i += 256) {
        int c = i >> 10, rem = i & 1023;
        xv[c * 1056 + (rem >> 5) * 33 + (rem & 31)] = x[(size_t)b * 3072 + i];
    }
    for (int i = tid; i < 2400; i += 256) z2s[i] = ws[OFF_ZU2 + i];
    if (tid < 48) par2[tid] = ws[OFF_P2 + tid];
    __syncthreads();

    // ---- B: logmap0 over channels of x ----
    for (int p = tid; p < 1024; p += 256) {
        int base = (p >> 5) * 33 + (p & 31);
        float a0 = xv[base], a1 = xv[1056 + base], a2 = xv[2112 + base];
        float n2 = a0 * a0 + a1 * a1 + a2 * a2;
        float nn = fmaxf(fsqrt(n2), EPSF);
        float f = fast_atanh01(fminf(nn, 1.0f - 1e-7f)) * frcp(nn) * ratio1;
        xv[base] = a0 * f; xv[1056 + base] = a1 * f; xv[2112 + base] = a2 * f;
    }
    __syncthreads();

    // ---- C: conv1 + hrelu + pool (thread = pooled cell), fused logmap2 ----
    if (tid < 196) {
        const float* zug  = ws + OFF_ZU1;
        const float* parg = ws + OFF_P1;
        int ph = tid / 14, pw = tid % 14;
        int base0 = (2 * ph) * 33 + 2 * pw;
        float acc[4][6], n2w[4];
#pragma unroll
        for (int wi = 0; wi < 4; wi++) {
            n2w[wi] = 0.f;
#pragma unroll
            for (int o = 0; o < 6; o++) acc[wi][o] = 0.f;
        }
#pragma unroll 1
        for (int c = 0; c < 3; c++) {
            float px[6][6];
#pragma unroll
            for (int r = 0; r < 6; r++)
#pragma unroll
            for (int j = 0; j < 6; j++)
                px[r][j] = xv[c * 1056 + base0 + r * 33 + j];
#pragma unroll
            for (int fi = 0; fi < 5; fi++) {
                const float* zp = zug + (c * 5 + fi) * 30;   // wave-uniform
#pragma unroll
                for (int fj = 0; fj < 5; fj++) {
                    float zw[6];
#pragma unroll
                    for (int o = 0; o < 6; o++) zw[o] = zp[fj * 6 + o];
#pragma unroll
                    for (int dy = 0; dy < 2; dy++)
#pragma unroll
                    for (int dx = 0; dx < 2; dx++) {
                        float v = px[fi + dy][fj + dx];
                        int wi = dy * 2 + dx;
                        n2w[wi] = fmaf(v, v, n2w[wi]);
#pragma unroll
                        for (int o = 0; o < 6; o++) acc[wi][o] = fmaf(v, zw[o], acc[wi][o]);
                    }
                }
            }
        }
        float zn[6], chv[6], shv[6];
#pragma unroll
        for (int o = 0; o < 6; o++) { zn[o] = parg[o]; chv[o] = parg[6 + o]; shv[o] = parg[12 + o]; }
        float best[6]; float bestn = -1.f;
#pragma unroll
        for (int wi = 0; wi < 4; wi++) {
            float hn2 = chain_fast<6>(acc[wi], n2w[wi], zn, chv, shv);
            if (hn2 > bestn) {
                bestn = hn2;
#pragma unroll
                for (int o = 0; o < 6; o++) best[o] = acc[wi][o];
            }
        }
        float nn = fmaxf(fsqrt(bestn), EPSF);
        float f2 = fast_atanh01(fminf(nn, 1.0f - 1e-7f)) * frcp(nn) * ratio2;
#pragma unroll
        for (int o = 0; o < 6; o++) v2[o * 210 + ph * 15 + pw] = f2 * best[o];
    }
    __syncthreads();

    // ---- D: conv2 patch-norm row sums rs[r][x] = sum_c sum_j v2[c][r][x+j]^2
    if (tid < 140) {
        int r = tid / 10, xq = tid % 10;
        float ssum = 0.f;
#pragma unroll
        for (int c = 0; c < 6; c++)
#pragma unroll
        for (int j = 0; j < 5; j++) {
            float v = v2[c * 210 + r * 15 + xq + j];
            ssum = fmaf(v, v, ssum);
        }
        rs[tid] = ssum;
    }
    __syncthreads();

    // ---- E: conv2 + hrelu + pool + flatten. thread = (window-row wy, chan o)
    if (tid < 160) {
        int wy = tid >> 4, o = tid & 15;
        float acc[10];
#pragma unroll
        for (int w = 0; w < 10; w++) acc[w] = 0.f;
#pragma unroll 1
        for (int c = 0; c < 6; c++) {
#pragma unroll 1
            for (int fi = 0; fi < 5; fi++) {
                float px[14];
#pragma unroll
                for (int k = 0; k < 14; k++) px[k] = v2[c * 210 + (wy + fi) * 15 + k];
#pragma unroll
                for (int fj = 0; fj < 5; fj++) {
                    float zw = z2s[((c * 5 + fi) * 5 + fj) * 16 + o];
#pragma unroll
                    for (int w = 0; w < 10; w++)
                        acc[w] = fmaf(px[w + fj], zw, acc[w]);
                }
            }
        }
        float znl = par2[o], chv = par2[16 + o], shv = par2[32 + o];
        float val[10], hn2v[10];
#pragma unroll
        for (int w = 0; w < 10; w++) {
            float n2 = rs[wy * 10 + w] + rs[(wy + 1) * 10 + w] + rs[(wy + 2) * 10 + w]
                     + rs[(wy + 3) * 10 + w] + rs[(wy + 4) * 10 + w];
            float nn = fmaxf(fsqrt(n2), EPSF);
            float t = fast_tanh_pos(nn);
            float s = t * frcp(nn) * fminf(1.0f, MAXN * frcp(fmaxf(t, EPSF)));
            float cx2 = (s * s) * n2;
            float rden = frcp(fmaxf(1.0f - cx2, EPSF));
            float arg = (2.0f * (s * acc[w]) * chv - (1.0f + cx2) * shv) * rden;
            float y = sinh_k_asinh(arg, 2.0f * znl);
            float p = y * y;
#pragma unroll
            for (int d = 1; d < 16; d <<= 1) p += __shfl_xor(p, d);
            float ys2 = p;
            float dnm = 1.0f + fsqrt(1.0f + ys2);
            float ny2 = ys2 * frcp(dnm * dnm);
            float ny = fmaxf(fsqrt(ny2), EPSF);
            float pf = fminf(1.0f, MAXN * frcp(ny));
            float sc = pf * frcp(dnm);
            float n2b = pf * pf * ny2;
            float nb = fmaxf(fsqrt(n2b), EPSF);
            float fb = fast_atanh01(fminf(nb, 1.0f - 1e-7f)) * frcp(nb);
            float u = fmaxf(fb * sc * y, 0.f);
            float q = u * u;
#pragma unroll
            for (int d = 1; d < 16; d <<= 1) q += __shfl_xor(q, d);
            float m2 = q;
            float m = fmaxf(fsqrt(m2), EPSF);
            float tm = fast_tanh_pos(m);
            float g = tm * frcp(m) * fminf(1.0f, MAXN * frcp(fmaxf(tm, EPSF)));
            val[w] = g * u;
            hn2v[w] = g * g * m2;
        }
        // pool 2x2 (first-max semantics) + flatten logmap factor
        float part = 0.f;
#pragma unroll
        for (int pw = 0; pw < 5; pw++) {
            int i0 = 2 * pw, i1 = i0 + 1;
            bool firstcol = hn2v[i0] >= hn2v[i1];
            float iu = firstcol ? val[i0]  : val[i1];
            float ih = firstcol ? hn2v[i0] : hn2v[i1];
            float pu  = __shfl_xor(iu, 16);   // partner row (wy ^ 1)
            float phh = __shfl_xor(ih, 16);
            if ((wy & 1) == 0) {
                bool top = ih >= phh;
                float wu = top ? iu : pu;
                float wh = top ? ih : phh;
                float nn = fmaxf(fsqrt(wh), EPSF);
                float f3 = fast_atanh01(fminf(nn, 1.0f - 1e-7f)) * frcp(nn) * ratio3;
                u3[o * 25 + (wy >> 1) * 5 + pw] = f3 * wu;
                if (o == 0) part = fmaf(f3 * f3, wh, part);
            }
        }
        if ((wy & 1) == 0 && o == 0) spart[wy >> 1] = part;
    }
    __syncthreads();

    // ---- F: flatten expmap scale + FC stack ----
    float S = spart[0] + spart[1] + spart[2] + spart[3] + spart[4];
    float nnS = fmaxf(fsqrt(S), EPSF);
    float tS = fast_tanh_pos(nnS);
    float gflat = tS * frcp(nnS) * fminf(1.0f, MAXN * frcp(fmaxf(tS, EPSF)));
    float cx2a = gflat * gflat * S;

    float g1, g2, gd;
    float cx2b = fc_block<400, 120, true >(tid, u3, gflat, cx2a, zf1, ws + OFF_PF1, h1, rbuf, g1);
    float cx2c = fc_block<120, 84,  true >(tid, h1, g1,   cx2b, zf2, ws + OFF_PF2, h2, rbuf, g2);
    fc_block<84, 10, false>(tid, h2, g2, cx2c, zf3, ws + OFF_PF3, out + (size_t)b * 10, rbuf, gd);
}

// ---------------------------------------------------------------------------
static double beta_fn(double n) {
    return exp(lgamma(n / 2.0) + lgamma(0.5) - lgamma((n + 1) / 2.0));
}

extern "C" void kernel_launch(void* const* d_in, const int* in_sizes, int n_in,
                              void* d_out, int out_size, void* d_ws, size_t ws_size,
                              hipStream_t stream) {
    (void)in_sizes; (void)n_in; (void)out_size; (void)ws_size;
    const float* x   = (const float*)d_in[0];
    const float* z1  = (const float*)d_in[1];
    const float* b1  = (const float*)d_in[2];
    const float* z2  = (const float*)d_in[3];
    const float* b2  = (const float*)d_in[4];
    const float* zf1 = (const float*)d_in[5];
    const float* bf1 = (const float*)d_in[6];
    const float* zf2 = (const float*)d_in[7];
    const float* bf2 = (const float*)d_in[8];
    const float* zf3 = (const float*)d_in[9];
    const float* bf3 = (const float*)d_in[10];
    float* out = (float*)d_out;
    float* ws  = (float*)d_ws;

    const float ratio1 = (float)(beta_fn(75.0)  / beta_fn(3.0));
    const float ratio2 = (float)(beta_fn(150.0) / beta_fn(6.0));
    const float ratio3 = (float)(beta_fn(400.0) / beta_fn(16.0));

    init_kernel <<<1, 256, 0, stream>>>(b1, b2, bf1, bf2, bf3, ws);
    accum_kernel<<<242, 256, 0, stream>>>(z1, z2, zf1, zf2, zf3, ws);
    final_kernel<<<4, 256, 0, stream>>>(z1, z2, ws);
    mega_kernel <<<1024, 256, 0, stream>>>(x, ws, zf1, zf2, zf3, out,
                                           ratio1, ratio2, ratio3);
}